// Round 9
// baseline (31.445 us; speedup 1.0000x reference)
//
#include <hip/hip_runtime.h>
#include <math.h>

#define MAP_SIZE 256
#define KV 64
#define HPX (1.0f / 256.0f)
#define TK 288539.0083f            // 2 * 100000 * log2(e)

__global__ __launch_bounds__(256) void cdm_pass1(
    const float* __restrict__ contour,   // (bn, KV, 2)
    float* __restrict__ out,             // (bn, 256, 256) unnormalized prod
    float* __restrict__ bmax)            // per-block max (no atomics)
{
    __shared__ float4 cv4[KV / 2];       // vertex pairs (2j, 2j+1)
    const int blocksPerImg = (MAP_SIZE * MAP_SIZE) / 256;  // 256
    const int bn  = blockIdx.x / blocksPerImg;
    const int pix = (blockIdx.x % blocksPerImg) * 256 + threadIdx.x;

    if (threadIdx.x < KV / 2)
        cv4[threadIdx.x] = ((const float4*)contour)[bn * (KV / 2) + threadIdx.x];
    __syncthreads();

    const float mx = (float)(pix >> 8) * HPX;
    const float my = (float)(pix & 255) * HPX;

    const float4 q0 = cv4[0];
    float ax = q0.x - mx;                // carried: A - m
    float ay = q0.y - my;
    float u  = __builtin_copysignf(1.0f, ay);  // carried sign of dy

    float mindd = 1e30f;
    float wn2   = 0.0f;                  // winding number (exact small-int floats)
    float corr  = 0.0f;                  // tanh-vs-sign deviation sum

    // Pure float-pipe edge pass: NO v_cmp / SALU / cndmask.
    //   crossing contrib = (d - c*d^2)/2, d = (u'-u)/2, c = sign(cr)
    //   corr += sign(cr) * [dot<0] * 1/(exp(2K|cr|)+1)   ([dot<0] = 0.5-0.5*sign(dot))
    auto edge = [&](float bx, float by) {
        const float rx = bx - mx;
        const float ry = by - my;
        const float rr = fmaf(rx, rx, ry * ry);
        mindd = fminf(mindd, rr);
        const float cr = fmaf(ay, rx, -ax * ry);
        const float dt = fmaf(ax, rx, ay * ry);
        const float un = __builtin_copysignf(1.0f, ry);
        const float c  = __builtin_copysignf(1.0f, cr);
        const float dl = (un - u) * 0.5f;
        wn2 = fmaf(dl * fmaf(-c, dl, 1.0f), 0.5f, wn2);
        const float e  = __builtin_amdgcn_exp2f(__builtin_fabsf(cr) * TK);
        const float d2 = __builtin_amdgcn_rcpf(e + 1.0f);
        const float w  = fmaf(-0.5f, __builtin_copysignf(1.0f, dt), 0.5f);
        corr = fmaf(c * d2, w, corr);
        ax = rx; ay = ry; u = un;
    };

    edge(q0.z, q0.w);                   // v0 -> v1
    #pragma unroll 4
    for (int jj = 1; jj < KV / 2; ++jj) {
        const float4 t = cv4[jj];
        edge(t.x, t.y);                 // -> v(2jj)
        edge(t.z, t.w);                 // -> v(2jj+1)
    }
    edge(q0.x, q0.y);                   // wrap v63 -> v0

    const float resize = __builtin_fabsf(wn2 + corr);
    const float pv = resize * __builtin_amdgcn_sqrtf(mindd);
    out[bn * (MAP_SIZE * MAP_SIZE) + pix] = pv;

    // block max -> plain store (no global atomic)
    float m = pv;
    #pragma unroll
    for (int off = 32; off > 0; off >>= 1)
        m = fmaxf(m, __shfl_xor(m, off));

    __shared__ float wmax[4];
    const int lane = threadIdx.x & 63;
    const int wid  = threadIdx.x >> 6;
    if (lane == 0) wmax[wid] = m;
    __syncthreads();
    if (threadIdx.x == 0)
        bmax[blockIdx.x] = fmaxf(fmaxf(wmax[0], wmax[1]), fmaxf(wmax[2], wmax[3]));
}

__global__ __launch_bounds__(256) void cdm_pass2(
    float4* __restrict__ out, const float* __restrict__ bmax, int nb, int n4)
{
    // every block re-reduces the block-max array (8 KB, L2-resident)
    float m = 0.0f;
    for (int i = threadIdx.x; i < nb; i += 256) m = fmaxf(m, bmax[i]);
    #pragma unroll
    for (int off = 32; off > 0; off >>= 1)
        m = fmaxf(m, __shfl_xor(m, off));

    __shared__ float wm[4];
    if ((threadIdx.x & 63) == 0) wm[threadIdx.x >> 6] = m;
    __syncthreads();
    const float gm  = fmaxf(fmaxf(wm[0], wm[1]), fmaxf(wm[2], wm[3]));
    const float inv = 1.0f / gm;

    const int i = blockIdx.x * 256 + threadIdx.x;
    if (i < n4) {
        float4 v = out[i];
        v.x *= inv; v.y *= inv; v.z *= inv; v.w *= inv;
        out[i] = v;
    }
}

extern "C" void kernel_launch(void* const* d_in, const int* in_sizes, int n_in,
                              void* d_out, int out_size, void* d_ws, size_t ws_size,
                              hipStream_t stream) {
    const float* contour = (const float*)d_in[0];
    float* out  = (float*)d_out;
    float* bmax = (float*)d_ws;

    const int bn = in_sizes[0] / (KV * 2);            // 8
    const int npix = bn * MAP_SIZE * MAP_SIZE;        // 524288 == out_size

    const int blocksPerImg = (MAP_SIZE * MAP_SIZE) / 256;  // 256
    const int nb = bn * blocksPerImg;                       // 2048
    cdm_pass1<<<nb, 256, 0, stream>>>(contour, out, bmax);

    const int n4 = npix / 4;
    cdm_pass2<<<(n4 + 255) / 256, 256, 0, stream>>>((float4*)out, bmax, nb, n4);
}

// Round 10
// 24.849 us; speedup vs baseline: 1.2655x; 1.2655x over previous
//
#include <hip/hip_runtime.h>
#include <math.h>

#define MAP_SIZE 256
#define KV 64
#define HPX (1.0f / 256.0f)
#define TK 288539.0083f            // 2 * 100000 * log2(e)

__global__ __launch_bounds__(256) void cdm_pass1(
    const float* __restrict__ contour,   // (bn, KV, 2)
    float* __restrict__ out,             // (bn, 256, 256) unnormalized prod
    float* __restrict__ bmax)            // per-block max (no atomics)
{
    __shared__ float4 cv4[KV / 2];       // vertex pairs (2j, 2j+1)
    const int blocksPerImg = (MAP_SIZE * MAP_SIZE) / 256;  // 256
    const int bn  = blockIdx.x / blocksPerImg;
    const int pix = (blockIdx.x % blocksPerImg) * 256 + threadIdx.x;

    if (threadIdx.x < KV / 2)
        cv4[threadIdx.x] = ((const float4*)contour)[bn * (KV / 2) + threadIdx.x];
    __syncthreads();

    const float mx = (float)(pix >> 8) * HPX;
    const float my = (float)(pix & 255) * HPX;

    const float4 q0 = cv4[0];
    float ax = q0.x - mx;                // carried: A - m
    float ay = q0.y - my;
    float u  = __builtin_copysignf(1.0f, ay);  // carried sign of dy

    float mindd = 1e30f;
    float wn2   = 0.0f;                  // winding number (exact small-int floats)
    float macr  = 1e30f;                 // min |cr| over edges
    float scr   = 1.0f;                  // cr of argmin edge
    float sdt   = 1.0f;                  // dot of argmin edge

    // ZERO-TRANS edge pass. Deviation term handled once in epilogue via the
    // argmin-|cr| edge (d2 decays ~2^29 per 1e-4 of |cr| -> min term dominates).
    auto edge = [&](float bx, float by) {
        const float rx = bx - mx;
        const float ry = by - my;
        const float rr = fmaf(rx, rx, ry * ry);
        mindd = fminf(mindd, rr);
        const float cr = fmaf(ay, rx, -ax * ry);
        const float dt = fmaf(ax, rx, ay * ry);
        const float un = __builtin_copysignf(1.0f, ry);
        const float c  = __builtin_copysignf(1.0f, cr);
        const float dl = (un - u) * 0.5f;
        wn2 = fmaf(dl * fmaf(-c, dl, 1.0f), 0.5f, wn2);
        const float acr = __builtin_fabsf(cr);
        const bool better = acr < macr;          // v_cmp (abs src mods)
        macr = fminf(acr, macr);
        scr  = better ? cr : scr;                // v_cndmask
        sdt  = better ? dt : sdt;                // v_cndmask
        ax = rx; ay = ry; u = un;
    };

    edge(q0.z, q0.w);                   // v0 -> v1
    #pragma unroll 4
    for (int jj = 1; jj < KV / 2; ++jj) {
        const float4 t = cv4[jj];
        edge(t.x, t.y);                 // -> v(2jj)
        edge(t.z, t.w);                 // -> v(2jj+1)
    }
    edge(q0.x, q0.y);                   // wrap v63 -> v0

    // epilogue: single trans evaluation for the dominant deviation term
    const float e    = __builtin_amdgcn_exp2f(macr * TK);
    const float d2   = __builtin_amdgcn_rcpf(e + 1.0f);
    const float w    = fmaf(-0.5f, __builtin_copysignf(1.0f, sdt), 0.5f); // [dot<0]
    const float corr = __builtin_copysignf(1.0f, scr) * d2 * w;

    const float resize = __builtin_fabsf(wn2 + corr);
    const float pv = resize * __builtin_amdgcn_sqrtf(mindd);
    out[bn * (MAP_SIZE * MAP_SIZE) + pix] = pv;

    // block max -> plain store (no global atomic)
    float m = pv;
    #pragma unroll
    for (int off = 32; off > 0; off >>= 1)
        m = fmaxf(m, __shfl_xor(m, off));

    __shared__ float wmax[4];
    const int lane = threadIdx.x & 63;
    const int wid  = threadIdx.x >> 6;
    if (lane == 0) wmax[wid] = m;
    __syncthreads();
    if (threadIdx.x == 0)
        bmax[blockIdx.x] = fmaxf(fmaxf(wmax[0], wmax[1]), fmaxf(wmax[2], wmax[3]));
}

__global__ __launch_bounds__(256) void cdm_pass2(
    float4* __restrict__ out, const float* __restrict__ bmax, int nb, int n4)
{
    // every block re-reduces the block-max array (8 KB, L2-resident)
    float m = 0.0f;
    for (int i = threadIdx.x; i < nb; i += 256) m = fmaxf(m, bmax[i]);
    #pragma unroll
    for (int off = 32; off > 0; off >>= 1)
        m = fmaxf(m, __shfl_xor(m, off));

    __shared__ float wm[4];
    if ((threadIdx.x & 63) == 0) wm[threadIdx.x >> 6] = m;
    __syncthreads();
    const float gm  = fmaxf(fmaxf(wm[0], wm[1]), fmaxf(wm[2], wm[3]));
    const float inv = 1.0f / gm;

    const int i = blockIdx.x * 256 + threadIdx.x;
    if (i < n4) {
        float4 v = out[i];
        v.x *= inv; v.y *= inv; v.z *= inv; v.w *= inv;
        out[i] = v;
    }
}

extern "C" void kernel_launch(void* const* d_in, const int* in_sizes, int n_in,
                              void* d_out, int out_size, void* d_ws, size_t ws_size,
                              hipStream_t stream) {
    const float* contour = (const float*)d_in[0];
    float* out  = (float*)d_out;
    float* bmax = (float*)d_ws;

    const int bn = in_sizes[0] / (KV * 2);            // 8
    const int npix = bn * MAP_SIZE * MAP_SIZE;        // 524288 == out_size

    const int blocksPerImg = (MAP_SIZE * MAP_SIZE) / 256;  // 256
    const int nb = bn * blocksPerImg;                       // 2048
    cdm_pass1<<<nb, 256, 0, stream>>>(contour, out, bmax);

    const int n4 = npix / 4;
    cdm_pass2<<<(n4 + 255) / 256, 256, 0, stream>>>((float4*)out, bmax, nb, n4);
}